// Round 17
// baseline (657.022 us; speedup 1.0000x reference)
//
#include <hip/hip_runtime.h>
#include <hip/hip_bf16.h>

#define B_ 2
#define T_ 128
#define U_ 64
#define H_ 1024
#define NO_ 5001

typedef __attribute__((ext_vector_type(8))) short bf16x8;
typedef __attribute__((ext_vector_type(4))) float f32x4;

__device__ __forceinline__ float bf2f(unsigned short s) {
  unsigned int u = ((unsigned int)s) << 16;
  float f; __builtin_memcpy(&f, &u, 4); return f;
}
__device__ __forceinline__ unsigned short f2bf(float f) {
  unsigned int u; __builtin_memcpy(&u, &f, 4);
  u = u + 0x7FFFu + ((u >> 16) & 1u);   // round-to-nearest-even
  return (unsigned short)(u >> 16);
}
__device__ __forceinline__ float fsig(float x) {
  x = fminf(fmaxf(x, -30.f), 30.f);
  float e = __expf(-x);
  return __builtin_amdgcn_rcpf(1.f + e);
}
__device__ __forceinline__ float ftanh(float x) {
  x = fminf(fmaxf(x, -15.f), 15.f);
  float e = __expf(2.f * x);
  return (e - 1.f) * __builtin_amdgcn_rcpf(e + 1.f);
}

__device__ __forceinline__ void gload_lds16(const unsigned short* g, unsigned short* l) {
  __builtin_amdgcn_global_load_lds(
      (const __attribute__((address_space(1))) unsigned int*)g,
      (__attribute__((address_space(3))) unsigned int*)l,
      16, 0, 0);
}

// ---------------- merged f32->bf16 conversions + bias pad + embed (one dispatch) ----------------
#define R_OUTW 1280256
#define R_WIH  (R_OUTW + 2097152)
#define R_WHH  (R_WIH + 2097152)
#define R_ENCW (R_WHH + 262144)
#define R_PRDW (R_ENCW + 262144)
#define R_ENC  (R_PRDW + 65536)
#define R_BIAS (R_ENC + 1280)
#define R_EMB  (R_BIAS + 32768)     // embed: B*U*H/4 float4 chunks

__global__ void k_cvt_all(
    const float* __restrict__ outW, const float* __restrict__ Wih,
    const float* __restrict__ Whh,  const float* __restrict__ encW,
    const float* __restrict__ prdW, const float* __restrict__ enc,
    const float* __restrict__ outB,
    const int* __restrict__ tg, const float* __restrict__ em,
    unsigned short* __restrict__ outW_bf, unsigned short* __restrict__ Wih_bf,
    unsigned short* __restrict__ Whh_bf,  unsigned short* __restrict__ encW_bf,
    unsigned short* __restrict__ prdW_bf, unsigned short* __restrict__ enc_bf,
    float* __restrict__ biasPad, unsigned short* __restrict__ x0_bf)
{
  int i = blockIdx.x * 256 + threadIdx.x;
  const float* src; unsigned short* dst; int off;
  if (i < R_OUTW)      { src = outW; dst = outW_bf; off = i; }
  else if (i < R_WIH)  { src = Wih;  dst = Wih_bf;  off = i - R_OUTW; }
  else if (i < R_WHH)  { src = Whh;  dst = Whh_bf;  off = i - R_WIH; }
  else if (i < R_ENCW) { src = encW; dst = encW_bf; off = i - R_WHH; }
  else if (i < R_PRDW) { src = prdW; dst = prdW_bf; off = i - R_ENCW; }
  else if (i < R_ENC)  { src = enc;  dst = enc_bf;  off = i - R_PRDW; }
  else if (i < R_BIAS) {
    int e0 = (i - R_ENC) * 4;
    float4 v;
    v.x = (e0 + 0 < NO_) ? outB[e0 + 0] : 0.f;
    v.y = (e0 + 1 < NO_) ? outB[e0 + 1] : 0.f;
    v.z = (e0 + 2 < NO_) ? outB[e0 + 2] : 0.f;
    v.w = (e0 + 3 < NO_) ? outB[e0 + 3] : 0.f;
    *(float4*)&biasPad[e0] = v;
    return;
  } else {                               // embedding gather -> bf16
    int idx = i - R_BIAS;                // [0, B*U*H/4)
    int bu = idx >> 8;
    int kc = (idx & 255) << 2;
    int t = tg[bu];
    const float4 v = *(const float4*)&em[(long)t * H_ + kc];
    ushort4 o; o.x = f2bf(v.x); o.y = f2bf(v.y); o.z = f2bf(v.z); o.w = f2bf(v.w);
    *(ushort4*)&x0_bf[bu * H_ + kc] = o;
    return;
  }
  const float4 v = ((const float4*)src)[off];
  ushort4 o;
  o.x = f2bf(v.x); o.y = f2bf(v.y); o.z = f2bf(v.z); o.w = f2bf(v.w);
  ((ushort4*)dst)[off] = o;
}

// ---------------- ep + pp projections in ONE launch (grid (8,3)) ----------------
__global__ __launch_bounds__(256) void gemm_proj(
    const unsigned short* __restrict__ enc_bf, const unsigned short* __restrict__ x2_bf,
    const unsigned short* __restrict__ encW_bf, const unsigned short* __restrict__ prdW_bf,
    const float* __restrict__ encB, const float* __restrict__ prdB,
    float* __restrict__ ep, float* __restrict__ pp)
{
  __shared__ unsigned short As[128 * 32];
  __shared__ unsigned short Bs[128 * 32];
  const int tid = threadIdx.x;
  const unsigned short* A; const unsigned short* W; const float* b1; float* C;
  int m0;
  if (blockIdx.y < 2) { A = enc_bf; W = encW_bf; b1 = encB; C = ep; m0 = blockIdx.y * 128; }
  else                { A = x2_bf;  W = prdW_bf; b1 = prdB; C = pp; m0 = 0; }
  const int n0 = blockIdx.x * 128;
  const int K = H_, N = H_;
  const int lane = tid & 63, w = tid >> 6;
  const int wr = (w >> 1) * 64, wc = (w & 1) * 64;
  const int lr = lane & 15, lk = (lane >> 4) * 8;
  f32x4 acc[4][4] = {};

  for (int k0 = 0; k0 < K; k0 += 32) {
#pragma unroll
    for (int s = 0; s < 2; ++s) {
      int idx = (w * 2 + s) * 64 + lane;
      int row = idx >> 2, c8 = (idx & 3) * 8;
      gload_lds16(&A[(long)(m0 + row) * K + k0 + c8], &As[(w * 2 + s) * 512]);
      gload_lds16(&W[(long)(n0 + row) * K + k0 + c8], &Bs[(w * 2 + s) * 512]);
    }
    __syncthreads();
    bf16x8 aF[4], bF[4];
#pragma unroll
    for (int i = 0; i < 4; ++i) {
      aF[i] = *(const bf16x8*)&As[(wr + i * 16 + lr) * 32 + lk];
      bF[i] = *(const bf16x8*)&Bs[(wc + i * 16 + lr) * 32 + lk];
    }
#pragma unroll
    for (int i = 0; i < 4; ++i)
#pragma unroll
      for (int j = 0; j < 4; ++j)
        acc[i][j] = __builtin_amdgcn_mfma_f32_16x16x32_bf16(aF[i], bF[j], acc[i][j], 0, 0, 0);
    __syncthreads();
  }

  const int lq = (lane >> 4) * 4;
#pragma unroll
  for (int j = 0; j < 4; ++j) {
    int col = n0 + wc + j * 16 + lr;
    float bb = b1[col];
#pragma unroll
    for (int i = 0; i < 4; ++i) {
      int rowg = m0 + wr + i * 16 + lq;
#pragma unroll
      for (int r = 0; r < 4; ++r)
        C[(long)(rowg + r) * N + col] = acc[i][j][r] + bb;
    }
  }
}

// ---------------- 256x256 pipelined logits GEMM (round-8/13 proven version) ----------------
#define STAGE_A(kt2, kh, rb) \
  gload_lds16(aSrc[rb] + (kt2) * 64 + (kh) * 32, \
              &As_f[((((kt2) & 1) * 2 + (kh)) * 8192) + ((rb) * 128 + wv * 16) * 32])
#define STAGE_B(kt2, kh, rb) \
  gload_lds16(bSrc[rb] + (kt2) * 64 + (kh) * 32, \
              &Bs_f[((((kt2) & 1) * 2 + (kh)) * 8192) + ((rb) * 128 + wv * 16) * 32])

__global__ __launch_bounds__(512, 1) void gemm_logits(
    const unsigned short* __restrict__ A, const unsigned short* __restrict__ W,
    const float* __restrict__ biasPad, float* __restrict__ C, int M, int N, int K)
{
  __shared__ __align__(16) unsigned short lds_all[65536];   // 128 KB
  unsigned short* As_f = lds_all;
  unsigned short* Bs_f = lds_all + 32768;
  const int tid = threadIdx.x;
  const int lane = tid & 63, wv = tid >> 6;
  const int wm = wv >> 2, wn = wv & 3;
  int swzb = (blockIdx.x & 7) * 160 + (blockIdx.x >> 3);
  const int n0 = (swzb >> 6) * 256;
  const int m0 = (swzb & 63) * 256;
  const int NT = K / 64;

  const unsigned short* aSrc[2];
  const unsigned short* bSrc[2];
#pragma unroll
  for (int rb = 0; rb < 2; ++rb) {
    int rl = rb * 128 + (tid >> 2);
    int c2s = (tid & 3) ^ ((rl >> 1) & 3);
    aSrc[rb] = A + (long)(m0 + rl) * K + c2s * 8;
    bSrc[rb] = W + (long)(n0 + rl) * K + c2s * 8;
  }
  int aOff[8], bOff[4];
#pragma unroll
  for (int i = 0; i < 8; ++i) {
    int r = wm * 128 + i * 16 + (lane & 15);
    aOff[i] = r * 32 + (((lane >> 4) ^ ((r >> 1) & 3)) * 8);
  }
#pragma unroll
  for (int j = 0; j < 4; ++j) {
    int r = wn * 64 + j * 16 + (lane & 15);
    bOff[j] = r * 32 + (((lane >> 4) ^ ((r >> 1) & 3)) * 8);
  }

  f32x4 acc[8][4] = {};

  STAGE_A(0, 0, 0); STAGE_A(0, 0, 1); STAGE_B(0, 0, 0); STAGE_B(0, 0, 1);
  STAGE_A(0, 1, 0); STAGE_A(0, 1, 1); STAGE_B(0, 1, 0); STAGE_B(0, 1, 1);

  for (int kt = 0; kt < NT; ++kt) {
    const int b = kt & 1;
    asm volatile("s_waitcnt vmcnt(4)" ::: "memory");
    __builtin_amdgcn_s_barrier();
    __builtin_amdgcn_sched_barrier(0);
    {   // phase 0: khalf 0
      const int base = (b * 2 + 0) * 8192;
      bf16x8 aF[8], bF[4];
#pragma unroll
      for (int i = 0; i < 8; ++i) aF[i] = *(const bf16x8*)&As_f[base + aOff[i]];
#pragma unroll
      for (int j = 0; j < 4; ++j) bF[j] = *(const bf16x8*)&Bs_f[base + bOff[j]];
      if (kt + 1 < NT) {
        STAGE_A(kt + 1, 0, 0); STAGE_A(kt + 1, 0, 1);
        STAGE_B(kt + 1, 0, 0); STAGE_B(kt + 1, 0, 1);
        STAGE_A(kt + 1, 1, 0); STAGE_A(kt + 1, 1, 1);
      }
      __builtin_amdgcn_s_setprio(1);
#pragma unroll
      for (int i = 0; i < 8; ++i)
#pragma unroll
        for (int j = 0; j < 4; ++j)
          acc[i][j] = __builtin_amdgcn_mfma_f32_16x16x32_bf16(aF[i], bF[j], acc[i][j], 0, 0, 0);
      __builtin_amdgcn_s_setprio(0);
    }
    if (kt + 1 < NT) { asm volatile("s_waitcnt vmcnt(6)" ::: "memory"); }
    else             { asm volatile("s_waitcnt vmcnt(0)" ::: "memory"); }
    __builtin_amdgcn_s_barrier();
    __builtin_amdgcn_sched_barrier(0);
    {   // phase 1: khalf 1
      const int base = (b * 2 + 1) * 8192;
      bf16x8 aF[8], bF[4];
#pragma unroll
      for (int i = 0; i < 8; ++i) aF[i] = *(const bf16x8*)&As_f[base + aOff[i]];
#pragma unroll
      for (int j = 0; j < 4; ++j) bF[j] = *(const bf16x8*)&Bs_f[base + bOff[j]];
      if (kt + 1 < NT) { STAGE_B(kt + 1, 1, 0); STAGE_B(kt + 1, 1, 1); }
      __builtin_amdgcn_s_setprio(1);
#pragma unroll
      for (int i = 0; i < 8; ++i)
#pragma unroll
        for (int j = 0; j < 4; ++j)
          acc[i][j] = __builtin_amdgcn_mfma_f32_16x16x32_bf16(aF[i], bF[j], acc[i][j], 0, 0, 0);
      __builtin_amdgcn_s_setprio(0);
    }
  }

  // epilogue: LDS-bounce, contiguous row writes
  float* eb = (float*)lds_all;               // [64][261] f32
  const int lq = (lane >> 4) * 4;
  float bv4[4];
#pragma unroll
  for (int j = 0; j < 4; ++j) bv4[j] = biasPad[n0 + wn * 64 + j * 16 + (lane & 15)];

#pragma unroll
  for (int cp = 0; cp < 4; ++cp) {
    __syncthreads();
#pragma unroll
    for (int ii = 0; ii < 2; ++ii) {
      int rbase = wm * 32 + ii * 16 + lq;
#pragma unroll
      for (int j = 0; j < 4; ++j) {
        int col = wn * 64 + j * 16 + (lane & 15);
#pragma unroll
        for (int r = 0; r < 4; ++r)
          eb[(rbase + r) * 261 + col] = acc[cp * 2 + ii][j][r] + bv4[j];
      }
    }
    __syncthreads();
    {
      int rl = tid >> 3, ci = tid & 7;
      long grow = (long)m0 + (rl >> 5) * 128 + cp * 32 + (rl & 31);
      float* crow = C + grow * N + n0;
      const float* er = &eb[rl * 261];
#pragma unroll
      for (int k = 0; k < 8; ++k) {
        int col = ci * 4 + k * 32;
        float4 v = *(const float4*)&er[col];
        int gc = n0 + col;
        if (gc + 4 <= N) {
          *(float4*)&crow[col] = v;
        } else if (gc < N) {
          float tmp[4] = {v.x, v.y, v.z, v.w};
#pragma unroll
          for (int e = 0; e < 4; ++e)
            if (gc + e < N) crow[col + e] = tmp[e];
        }
      }
    }
  }
}

// ---------------- joint = bf16(relu(enc_p[b,t,:] + prd_p[b,u,:])) ----------------
__global__ void k_joint(const float* __restrict__ ep, const float* __restrict__ pp,
                        unsigned short* __restrict__ jt)
{
  int idx = blockIdx.x * 256 + threadIdx.x;
  int m = idx >> 8;
  int kc = (idx & 255) << 2;
  int erow = m >> 6;
  int prow = (m >> 13) * U_ + (m & 63);
  const float4 e = *(const float4*)&ep[erow * H_ + kc];
  const float4 p = *(const float4*)&pp[prow * H_ + kc];
  float4 s;
  s.x = fmaxf(e.x + p.x, 0.f); s.y = fmaxf(e.y + p.y, 0.f);
  s.z = fmaxf(e.z + p.z, 0.f); s.w = fmaxf(e.w + p.w, 0.f);
  ushort4 o; o.x = f2bf(s.x); o.y = f2bf(s.y); o.z = f2bf(s.z); o.w = f2bf(s.w);
  *(ushort4*)&jt[m * H_ + kc] = o;
}

// ---------------- fused 2-layer wavefront LSTM, 4 groups x 64 blocks x 256 thr ----------------
// Round-17 change (L0/L1 only): the VALU h-dot (~0.9us/step, 34% VALUBusy) is
// replaced by MFMA: wave w == gate w computes C[16 gate-rows][2 batch] =
// Whh_frag x h_bf16 as 32 chained mfma_f32_16x16x32_bf16 (~0.1us). Fragment
// mapping identical to the proven gemm_bt (A row=lane&15, k=(lane>>4)*8;
// B col=lane&15 (batch; cols>=2 zero); C/D col=lane&15,row=(lane>>4)*4+r).
// The cross-wave part-reduce disappears (MFMA sums K internally); finale reads
// a 512B gate-LDS. h staged to LDS as bf16 adds SYNC-A (WAR-safe via the tag
// chain + SYNC-B; no ping-pong needed). L0/L1 h-poll loses its s_sleep (round-12
// config); X/flag polls keep backoff. X groups keep the VALU dot (slack).
__global__ __launch_bounds__(256, 1) void lstm_fused3(
    const unsigned short* __restrict__ x0_bf,
    const unsigned short* __restrict__ Whh0,
    const unsigned short* __restrict__ Wih0,
    const unsigned short* __restrict__ Whh1,
    const unsigned short* __restrict__ Wih1,
    const float* __restrict__ bih0, const float* __restrict__ bhh0,
    const float* __restrict__ bih1, const float* __restrict__ bhh1,
    unsigned short* __restrict__ x2_bf,
    float* __restrict__ hbuf0,
    float* __restrict__ hbuf1,
    float* __restrict__ xbuf,
    float* __restrict__ xg1buf, int* __restrict__ flags1,
    float* __restrict__ xg0buf, int* __restrict__ flags0)
{
  __shared__ float hs[2][H_];               // X groups: staged x (f32)
  __shared__ float part[2][4][64][2];       // X groups
  __shared__ unsigned short hbf[2][H_];     // L0/L1: staged h (bf16)
  __shared__ float gateS[4][2][16];         // L0/L1: per-gate MFMA results
  __shared__ float biasS[64];               // X groups

  const int tid = threadIdx.x;
  const int grp = blockIdx.x >> 6;           // 0=L0, 1=X1, 2=L1, 3=X0
  const int bid = blockIdx.x & 63;
  const int w = tid >> 6, l = tid & 63;
  const int g = l >> 4, q = l & 15;
  const int row = g * 1024 + bid * 16 + q;
  const int kb = w * 256;

#define DOT_BODY(WREG, SRC)                                                              \
  _Pragma("unroll")                                                                      \
  for (int it = 0; it < 32; ++it) {                                                      \
    bf16x8 wv = WREG[it];                                                                \
    float4 h0a = *(const float4*)&SRC[0][kb + it * 8];                                   \
    float4 h0b = *(const float4*)&SRC[0][kb + it * 8 + 4];                               \
    float4 h1a = *(const float4*)&SRC[1][kb + it * 8];                                   \
    float4 h1b = *(const float4*)&SRC[1][kb + it * 8 + 4];                               \
    a00 += bf2f((unsigned short)wv[0]) * h0a.x + bf2f((unsigned short)wv[4]) * h0b.x;    \
    a01 += bf2f((unsigned short)wv[1]) * h0a.y + bf2f((unsigned short)wv[5]) * h0b.y;    \
    a02 += bf2f((unsigned short)wv[2]) * h0a.z + bf2f((unsigned short)wv[6]) * h0b.z;    \
    a03 += bf2f((unsigned short)wv[3]) * h0a.w + bf2f((unsigned short)wv[7]) * h0b.w;    \
    a10 += bf2f((unsigned short)wv[0]) * h1a.x + bf2f((unsigned short)wv[4]) * h1b.x;    \
    a11 += bf2f((unsigned short)wv[1]) * h1a.y + bf2f((unsigned short)wv[5]) * h1b.y;    \
    a12 += bf2f((unsigned short)wv[2]) * h1a.z + bf2f((unsigned short)wv[6]) * h1b.z;    \
    a13 += bf2f((unsigned short)wv[3]) * h1a.w + bf2f((unsigned short)wv[7]) * h1b.w;    \
  }

  if (grp == 0 || grp == 2) {
    // ================= recurrent layers L0 / L1 (MFMA h-dot) =================
    const unsigned short* Whh = (grp == 0) ? Whh0 : Whh1;
    float* hbuf   = (grp == 0) ? hbuf0 : hbuf1;
    const float* xgbufR = (grp == 0) ? xg0buf : xg1buf;
    const int* flagsR   = (grp == 0) ? flags0 : flags1;
    // A-fragments: wave w = gate w; lane supplies row (l&15), k (l>>4)*8 of
    // each K=32 slice kt. 32 x bf16x8 = 128 VGPRs.
    bf16x8 wfrag[32];
    {
      const long arow = (long)(w * 1024 + bid * 16 + (l & 15)) * H_;
      const int klo = (l >> 4) * 8;
#pragma unroll
      for (int kt = 0; kt < 32; ++kt)
        wfrag[kt] = *(const bf16x8*)&Whh[arow + kt * 32 + klo];
    }
    const int klo = (l >> 4) * 8;
    const bool bactive = (l & 15) < 2;
    const unsigned short* hrow = &hbf[l & 15][klo];   // valid when bactive
    __syncthreads();

    float creg = 0.f;
    for (int u = 0; u < U_; ++u) {
      // finale lanes: flag poll (backoff) + issue 4 xg loads, bind deferred
      float xgi = 0.f, xgf = 0.f, xgg = 0.f, xgo = 0.f;
      if (tid < 32) {
        const int* fp = &flagsR[(u * 64 + bid) * 16];
        int fv;
        for (;;) {
          asm volatile("global_load_dword %0, %1, off sc1\n\ts_waitcnt vmcnt(0)"
                       : "=v"(fv) : "v"(fp) : "memory");
          if (fv != 0) break;
          __builtin_amdgcn_s_sleep(8);
        }
        const float* xb = &xgbufR[((u * 64 + bid) * 2 + (tid >> 4)) * 64];
        int qq = tid & 15;
        asm volatile("global_load_dword %0, %1, off sc1" : "=&v"(xgi) : "v"(xb + qq) : "memory");
        asm volatile("global_load_dword %0, %1, off sc1" : "=&v"(xgf) : "v"(xb + 16 + qq) : "memory");
        asm volatile("global_load_dword %0, %1, off sc1" : "=&v"(xgg) : "v"(xb + 32 + qq) : "memory");
        asm volatile("global_load_dword %0, %1, off sc1" : "=&v"(xgo) : "v"(xb + 48 + qq) : "memory");
      }
      if (u > 0) {
        // tight h-poll (critical path, no sleep)
        const float thr = 4.0f * u - 2.0f;
        const float* base = hbuf + (u & 1) * 2 * H_;
        const float* pa = base + tid * 4;
        const float* pb = base + H_ + tid * 4;
        float4 va, vb;
        for (;;) {
          asm volatile("global_load_dwordx4 %0, %2, off sc1\n\t"
                       "global_load_dwordx4 %1, %3, off sc1\n\t"
                       "s_waitcnt vmcnt(0)"
                       : "=v"(va), "=v"(vb) : "v"(pa), "v"(pb) : "memory");
          if (va.x > thr && va.y > thr && va.z > thr && va.w > thr &&
              vb.x > thr && vb.y > thr && vb.z > thr && vb.w > thr) break;
        }
        const float off = 4.0f * u;
        ushort4 ha, hb2;
        ha.x = f2bf(va.x - off); ha.y = f2bf(va.y - off);
        ha.z = f2bf(va.z - off); ha.w = f2bf(va.w - off);
        hb2.x = f2bf(vb.x - off); hb2.y = f2bf(vb.y - off);
        hb2.z = f2bf(vb.z - off); hb2.w = f2bf(vb.w - off);
        *(ushort4*)&hbf[0][tid * 4] = ha;
        *(ushort4*)&hbf[1][tid * 4] = hb2;
      }
      __syncthreads();                       // SYNC-A: hbf staged (cross-wave)
      f32x4 acc = {0.f, 0.f, 0.f, 0.f};
      if (u > 0) {
        bf16x8 zero8 = {};
#pragma unroll
        for (int kt = 0; kt < 32; ++kt) {
          bf16x8 bF = zero8;
          if (bactive) bF = *(const bf16x8*)&hrow[kt * 32];
          acc = __builtin_amdgcn_mfma_f32_16x16x32_bf16(wfrag[kt], bF, acc, 0, 0, 0);
        }
      }
      // extraction: lanes with col<2 hold gate[w][row][batch]
      if (bactive) {
        int b = l & 15;
        int r0 = (l >> 4) * 4;
#pragma unroll
        for (int r = 0; r < 4; ++r)
          gateS[w][b][r0 + r] = acc[r];
      }
      if (tid < 32) {   // bind xg loads before use
        asm volatile("s_waitcnt vmcnt(0)"
                     : "+v"(xgi), "+v"(xgf), "+v"(xgg), "+v"(xgo) :: "memory");
      }
      __syncthreads();                       // SYNC-B: gateS complete
      if (tid < 32) {
        int b = tid >> 4, qq = tid & 15;
        float gi = gateS[0][b][qq] + xgi;
        float gf = gateS[1][b][qq] + xgf;
        float gc = gateS[2][b][qq] + xgg;
        float go = gateS[3][b][qq] + xgo;
        float i_ = fsig(gi), f_ = fsig(gf), g_ = ftanh(gc), o_ = fsig(go);
        creg = f_ * creg + i_ * g_;
        float h = o_ * ftanh(creg);
        int j = bid * 16 + qq;
        if (grp == 0) {
          float tvx = h + 4.0f;
          const float* px = &xbuf[u * 2 * H_ + b * H_ + j];
          asm volatile("global_store_dword %0, %1, off sc1" :: "v"(px), "v"(tvx) : "memory");
        } else {
          x2_bf[(b * U_ + u) * H_ + j] = f2bf(h);
        }
        if (u < U_ - 1) {
          float tv = h + 4.0f * (u + 1);
          const float* pp2 = &hbuf[((u + 1) & 1) * 2 * H_ + b * H_ + j];
          asm volatile("global_store_dword %0, %1, off sc1" :: "v"(pp2), "v"(tv) : "memory");
        }
      }
    }
  } else {
    // ================= x-projection groups X1 (grp 1) / X0 (grp 3) =================
    const bool isX1 = (grp == 1);
    const unsigned short* Wih = isX1 ? Wih1 : Wih0;
    const float* bihp = isX1 ? bih1 : bih0;
    const float* bhhp = isX1 ? bhh1 : bhh0;
    float* xgbufW = isX1 ? xg1buf : xg0buf;
    int* flagsW   = isX1 ? flags1 : flags0;
    bf16x8 wreg[32];
#pragma unroll
    for (int it = 0; it < 32; ++it)
      wreg[it] = *(const bf16x8*)&Wih[(long)row * H_ + kb + it * 8];
    if (tid < 64) {
      int rr = (tid >> 4) * 1024 + bid * 16 + (tid & 15);
      biasS[tid] = bihp[rr] + bhhp[rr];
    }
    __syncthreads();

    for (int u = 0; u < U_; ++u) {
      const int p = u & 1;
      if (isX1) {
        const float* base = xbuf + u * 2 * H_;
        const float* pa = base + tid * 4;
        const float* pb = base + H_ + tid * 4;
        float4 va, vb;
        for (;;) {
          asm volatile("global_load_dwordx4 %0, %2, off sc1\n\t"
                       "global_load_dwordx4 %1, %3, off sc1\n\t"
                       "s_waitcnt vmcnt(0)"
                       : "=v"(va), "=v"(vb) : "v"(pa), "v"(pb) : "memory");
          if (va.x > 2.f && va.y > 2.f && va.z > 2.f && va.w > 2.f &&
              vb.x > 2.f && vb.y > 2.f && vb.z > 2.f && vb.w > 2.f) break;
          __builtin_amdgcn_s_sleep(8);
        }
        va.x -= 4.f; va.y -= 4.f; va.z -= 4.f; va.w -= 4.f;
        vb.x -= 4.f; vb.y -= 4.f; vb.z -= 4.f; vb.w -= 4.f;
        *(float4*)&hs[0][tid * 4] = va;
        *(float4*)&hs[1][tid * 4] = vb;
      } else {
        ushort4 xa = *(const ushort4*)&x0_bf[(0 * U_ + u) * H_ + tid * 4];
        ushort4 xb = *(const ushort4*)&x0_bf[(1 * U_ + u) * H_ + tid * 4];
        float4 va, vb;
        va.x = bf2f(xa.x); va.y = bf2f(xa.y); va.z = bf2f(xa.z); va.w = bf2f(xa.w);
        vb.x = bf2f(xb.x); vb.y = bf2f(xb.y); vb.z = bf2f(xb.z); vb.w = bf2f(xb.w);
        *(float4*)&hs[0][tid * 4] = va;
        *(float4*)&hs[1][tid * 4] = vb;
      }

      float a00 = 0.f, a01 = 0.f, a02 = 0.f, a03 = 0.f;
      float a10 = 0.f, a11 = 0.f, a12 = 0.f, a13 = 0.f;
      DOT_BODY(wreg, hs)
      part[p][w][l][0] = (a00 + a01) + (a02 + a03);
      part[p][w][l][1] = (a10 + a11) + (a12 + a13);
      __syncthreads();
      if (tid < 128) {
        int b = tid >> 6, ll = tid & 63;
        float s = part[p][0][ll][b] + part[p][1][ll][b] + part[p][2][ll][b]
                + part[p][3][ll][b] + biasS[ll];
        const float* pw = &xgbufW[((u * 64 + bid) * 2 + b) * 64 + ll];
        asm volatile("global_store_dword %0, %1, off sc1" :: "v"(pw), "v"(s) : "memory");
        asm volatile("s_waitcnt vmcnt(0)" ::: "memory");
      }
      __syncthreads();
      if (tid == 0) {
        int one = 1;
        const int* fp = &flagsW[(u * 64 + bid) * 16];
        asm volatile("global_store_dword %0, %1, off sc1" :: "v"(fp), "v"(one) : "memory");
      }
    }
  }
#undef DOT_BODY
}

extern "C" void kernel_launch(void* const* d_in, const int* in_sizes, int n_in,
                              void* d_out, int out_size, void* d_ws, size_t ws_size,
                              hipStream_t stream)
{
  const float* enc   = (const float*)d_in[0];
  const int*   tg    = (const int*)d_in[1];
  const float* em    = (const float*)d_in[2];
  const float* Wih   = (const float*)d_in[3];
  const float* Whh   = (const float*)d_in[4];
  const float* bih   = (const float*)d_in[5];
  const float* bhh   = (const float*)d_in[6];
  const float* encW  = (const float*)d_in[7];
  const float* encB  = (const float*)d_in[8];
  const float* prdW  = (const float*)d_in[9];
  const float* prdB  = (const float*)d_in[10];
  const float* outW  = (const float*)d_in[11];
  const float* outB  = (const float*)d_in[12];
  float* out = (float*)d_out;
  char* ws = (char*)d_ws;

  // workspace layout (bytes)
  unsigned short* outW_bf = (unsigned short*)(ws + 0);         // 10,485,760
  unsigned short* Wih_bf  = (unsigned short*)(ws + 10485760);
  unsigned short* Whh_bf  = (unsigned short*)(ws + 27262976);
  unsigned short* encW_bf = (unsigned short*)(ws + 44040192);
  unsigned short* prdW_bf = (unsigned short*)(ws + 46137344);
  unsigned short* enc_bf  = (unsigned short*)(ws + 48234496);
  unsigned short* x0_bf   = (unsigned short*)(ws + 48758784);
  unsigned short* x2_bf   = (unsigned short*)(ws + 49283072);
  float* xg1buf = (float*)(ws + 49545216);                     // 2MB, live during LSTM
  float* hbufL0 = (float*)(ws + 51642368);                     // 16,384
  unsigned short* jt = (unsigned short*)(ws + 51659008);       // 32MB -> ends 85,213,440
  // flags0/xg0buf alias the head of the jt region (time-disjoint: jt written by
  // k_joint only AFTER the LSTM completes) — proven since round 13.
  int*   flags0 = (int*)(ws + 51659008);                       // 262,144
  float* xg0buf = (float*)(ws + 51921152);                     // 2,097,152
  float* hbufL1 = (float*)(ws + 85213440);                     // 16,384
  float* biasPad = (float*)(ws + 85229824);                    // 20,480
  float* xbuf = (float*)(ws + 85250304);                       // 524,288
  int* flags1 = (int*)(ws + 85774592);                         // 262,144 -> 86,036,736
  float* ep = (float*)(ws + 49545216);                         // post-LSTM overlap w/ xg1buf
  float* pp = (float*)(ws + 49545216 + 1048576);

  hipMemsetAsync(hbufL0, 0, 16384, stream);
  hipMemsetAsync(hbufL1, 0, 86036736 - 85213440, stream);      // hbufL1..flags1 end
  hipMemsetAsync(flags0, 0, 262144, stream);

  k_cvt_all<<<R_EMB / 256, 256, 0, stream>>>(
      outW, Wih, Whh, encW, prdW, enc, outB, tg, em,
      outW_bf, Wih_bf, Whh_bf, encW_bf, prdW_bf, enc_bf, biasPad, x0_bf);

  // ---- fused 4-group LSTM (both input projections in-kernel) ----
  lstm_fused3<<<256, 256, 0, stream>>>(
      x0_bf,
      Whh_bf, Wih_bf,
      Whh_bf + 4096 * H_, Wih_bf + 4096 * H_,
      bih, bhh, bih + 4096, bhh + 4096,
      x2_bf, hbufL0, hbufL1, xbuf,
      xg1buf, flags1, xg0buf, flags0);

  // ---- projections (ep + pp in one launch) ----
  gemm_proj<<<dim3(8, 3), 256, 0, stream>>>(enc_bf, x2_bf, encW_bf, prdW_bf,
                                            encB, prdB, ep, pp);

  // ---- joint + logits ----
  k_joint<<<16384, 256, 0, stream>>>(ep, pp, jt);
  gemm_logits<<<1280, 512, 0, stream>>>(jt, outW_bf, biasPad, out, B_ * T_ * U_, NO_, H_);
}

// Round 18
// 593.215 us; speedup vs baseline: 1.1076x; 1.1076x over previous
//
#include <hip/hip_runtime.h>
#include <hip/hip_bf16.h>

#define B_ 2
#define T_ 128
#define U_ 64
#define H_ 1024
#define NO_ 5001

typedef __attribute__((ext_vector_type(8))) short bf16x8;
typedef __attribute__((ext_vector_type(4))) float f32x4;

__device__ __forceinline__ float bf2f(unsigned short s) {
  unsigned int u = ((unsigned int)s) << 16;
  float f; __builtin_memcpy(&f, &u, 4); return f;
}
__device__ __forceinline__ unsigned short f2bf(float f) {
  unsigned int u; __builtin_memcpy(&u, &f, 4);
  u = u + 0x7FFFu + ((u >> 16) & 1u);   // round-to-nearest-even
  return (unsigned short)(u >> 16);
}
__device__ __forceinline__ float fsig(float x) {
  x = fminf(fmaxf(x, -30.f), 30.f);
  float e = __expf(-x);
  return __builtin_amdgcn_rcpf(1.f + e);
}
__device__ __forceinline__ float ftanh(float x) {
  x = fminf(fmaxf(x, -15.f), 15.f);
  float e = __expf(2.f * x);
  return (e - 1.f) * __builtin_amdgcn_rcpf(e + 1.f);
}

__device__ __forceinline__ void gload_lds16(const unsigned short* g, unsigned short* l) {
  __builtin_amdgcn_global_load_lds(
      (const __attribute__((address_space(1))) unsigned int*)g,
      (__attribute__((address_space(3))) unsigned int*)l,
      16, 0, 0);
}

// ---------------- merged f32->bf16 conversions + bias pad + embed (one dispatch) ----------------
#define R_OUTW 1280256
#define R_WIH  (R_OUTW + 2097152)
#define R_WHH  (R_WIH + 2097152)
#define R_ENCW (R_WHH + 262144)
#define R_PRDW (R_ENCW + 262144)
#define R_ENC  (R_PRDW + 65536)
#define R_BIAS (R_ENC + 1280)
#define R_EMB  (R_BIAS + 32768)     // embed: B*U*H/4 float4 chunks

__global__ void k_cvt_all(
    const float* __restrict__ outW, const float* __restrict__ Wih,
    const float* __restrict__ Whh,  const float* __restrict__ encW,
    const float* __restrict__ prdW, const float* __restrict__ enc,
    const float* __restrict__ outB,
    const int* __restrict__ tg, const float* __restrict__ em,
    unsigned short* __restrict__ outW_bf, unsigned short* __restrict__ Wih_bf,
    unsigned short* __restrict__ Whh_bf,  unsigned short* __restrict__ encW_bf,
    unsigned short* __restrict__ prdW_bf, unsigned short* __restrict__ enc_bf,
    float* __restrict__ biasPad, unsigned short* __restrict__ x0_bf)
{
  int i = blockIdx.x * 256 + threadIdx.x;
  const float* src; unsigned short* dst; int off;
  if (i < R_OUTW)      { src = outW; dst = outW_bf; off = i; }
  else if (i < R_WIH)  { src = Wih;  dst = Wih_bf;  off = i - R_OUTW; }
  else if (i < R_WHH)  { src = Whh;  dst = Whh_bf;  off = i - R_WIH; }
  else if (i < R_ENCW) { src = encW; dst = encW_bf; off = i - R_WHH; }
  else if (i < R_PRDW) { src = prdW; dst = prdW_bf; off = i - R_ENCW; }
  else if (i < R_ENC)  { src = enc;  dst = enc_bf;  off = i - R_PRDW; }
  else if (i < R_BIAS) {
    int e0 = (i - R_ENC) * 4;
    float4 v;
    v.x = (e0 + 0 < NO_) ? outB[e0 + 0] : 0.f;
    v.y = (e0 + 1 < NO_) ? outB[e0 + 1] : 0.f;
    v.z = (e0 + 2 < NO_) ? outB[e0 + 2] : 0.f;
    v.w = (e0 + 3 < NO_) ? outB[e0 + 3] : 0.f;
    *(float4*)&biasPad[e0] = v;
    return;
  } else {                               // embedding gather -> bf16
    int idx = i - R_BIAS;                // [0, B*U*H/4)
    int bu = idx >> 8;
    int kc = (idx & 255) << 2;
    int t = tg[bu];
    const float4 v = *(const float4*)&em[(long)t * H_ + kc];
    ushort4 o; o.x = f2bf(v.x); o.y = f2bf(v.y); o.z = f2bf(v.z); o.w = f2bf(v.w);
    *(ushort4*)&x0_bf[bu * H_ + kc] = o;
    return;
  }
  const float4 v = ((const float4*)src)[off];
  ushort4 o;
  o.x = f2bf(v.x); o.y = f2bf(v.y); o.z = f2bf(v.z); o.w = f2bf(v.w);
  ((ushort4*)dst)[off] = o;
}

// ---------------- ep + pp projections in ONE launch (grid (8,3)) ----------------
__global__ __launch_bounds__(256) void gemm_proj(
    const unsigned short* __restrict__ enc_bf, const unsigned short* __restrict__ x2_bf,
    const unsigned short* __restrict__ encW_bf, const unsigned short* __restrict__ prdW_bf,
    const float* __restrict__ encB, const float* __restrict__ prdB,
    float* __restrict__ ep, float* __restrict__ pp)
{
  __shared__ unsigned short As[128 * 32];
  __shared__ unsigned short Bs[128 * 32];
  const int tid = threadIdx.x;
  const unsigned short* A; const unsigned short* W; const float* b1; float* C;
  int m0;
  if (blockIdx.y < 2) { A = enc_bf; W = encW_bf; b1 = encB; C = ep; m0 = blockIdx.y * 128; }
  else                { A = x2_bf;  W = prdW_bf; b1 = prdB; C = pp; m0 = 0; }
  const int n0 = blockIdx.x * 128;
  const int K = H_, N = H_;
  const int lane = tid & 63, w = tid >> 6;
  const int wr = (w >> 1) * 64, wc = (w & 1) * 64;
  const int lr = lane & 15, lk = (lane >> 4) * 8;
  f32x4 acc[4][4] = {};

  for (int k0 = 0; k0 < K; k0 += 32) {
#pragma unroll
    for (int s = 0; s < 2; ++s) {
      int idx = (w * 2 + s) * 64 + lane;
      int row = idx >> 2, c8 = (idx & 3) * 8;
      gload_lds16(&A[(long)(m0 + row) * K + k0 + c8], &As[(w * 2 + s) * 512]);
      gload_lds16(&W[(long)(n0 + row) * K + k0 + c8], &Bs[(w * 2 + s) * 512]);
    }
    __syncthreads();
    bf16x8 aF[4], bF[4];
#pragma unroll
    for (int i = 0; i < 4; ++i) {
      aF[i] = *(const bf16x8*)&As[(wr + i * 16 + lr) * 32 + lk];
      bF[i] = *(const bf16x8*)&Bs[(wc + i * 16 + lr) * 32 + lk];
    }
#pragma unroll
    for (int i = 0; i < 4; ++i)
#pragma unroll
      for (int j = 0; j < 4; ++j)
        acc[i][j] = __builtin_amdgcn_mfma_f32_16x16x32_bf16(aF[i], bF[j], acc[i][j], 0, 0, 0);
    __syncthreads();
  }

  const int lq = (lane >> 4) * 4;
#pragma unroll
  for (int j = 0; j < 4; ++j) {
    int col = n0 + wc + j * 16 + lr;
    float bb = b1[col];
#pragma unroll
    for (int i = 0; i < 4; ++i) {
      int rowg = m0 + wr + i * 16 + lq;
#pragma unroll
      for (int r = 0; r < 4; ++r)
        C[(long)(rowg + r) * N + col] = acc[i][j][r] + bb;
    }
  }
}

// ---------------- 256x256 pipelined logits GEMM (round-8/13 proven version) ----------------
#define STAGE_A(kt2, kh, rb) \
  gload_lds16(aSrc[rb] + (kt2) * 64 + (kh) * 32, \
              &As_f[((((kt2) & 1) * 2 + (kh)) * 8192) + ((rb) * 128 + wv * 16) * 32])
#define STAGE_B(kt2, kh, rb) \
  gload_lds16(bSrc[rb] + (kt2) * 64 + (kh) * 32, \
              &Bs_f[((((kt2) & 1) * 2 + (kh)) * 8192) + ((rb) * 128 + wv * 16) * 32])

__global__ __launch_bounds__(512, 1) void gemm_logits(
    const unsigned short* __restrict__ A, const unsigned short* __restrict__ W,
    const float* __restrict__ biasPad, float* __restrict__ C, int M, int N, int K)
{
  __shared__ __align__(16) unsigned short lds_all[65536];   // 128 KB
  unsigned short* As_f = lds_all;
  unsigned short* Bs_f = lds_all + 32768;
  const int tid = threadIdx.x;
  const int lane = tid & 63, wv = tid >> 6;
  const int wm = wv >> 2, wn = wv & 3;
  int swzb = (blockIdx.x & 7) * 160 + (blockIdx.x >> 3);
  const int n0 = (swzb >> 6) * 256;
  const int m0 = (swzb & 63) * 256;
  const int NT = K / 64;

  const unsigned short* aSrc[2];
  const unsigned short* bSrc[2];
#pragma unroll
  for (int rb = 0; rb < 2; ++rb) {
    int rl = rb * 128 + (tid >> 2);
    int c2s = (tid & 3) ^ ((rl >> 1) & 3);
    aSrc[rb] = A + (long)(m0 + rl) * K + c2s * 8;
    bSrc[rb] = W + (long)(n0 + rl) * K + c2s * 8;
  }
  int aOff[8], bOff[4];
#pragma unroll
  for (int i = 0; i < 8; ++i) {
    int r = wm * 128 + i * 16 + (lane & 15);
    aOff[i] = r * 32 + (((lane >> 4) ^ ((r >> 1) & 3)) * 8);
  }
#pragma unroll
  for (int j = 0; j < 4; ++j) {
    int r = wn * 64 + j * 16 + (lane & 15);
    bOff[j] = r * 32 + (((lane >> 4) ^ ((r >> 1) & 3)) * 8);
  }

  f32x4 acc[8][4] = {};

  STAGE_A(0, 0, 0); STAGE_A(0, 0, 1); STAGE_B(0, 0, 0); STAGE_B(0, 0, 1);
  STAGE_A(0, 1, 0); STAGE_A(0, 1, 1); STAGE_B(0, 1, 0); STAGE_B(0, 1, 1);

  for (int kt = 0; kt < NT; ++kt) {
    const int b = kt & 1;
    asm volatile("s_waitcnt vmcnt(4)" ::: "memory");
    __builtin_amdgcn_s_barrier();
    __builtin_amdgcn_sched_barrier(0);
    {   // phase 0: khalf 0
      const int base = (b * 2 + 0) * 8192;
      bf16x8 aF[8], bF[4];
#pragma unroll
      for (int i = 0; i < 8; ++i) aF[i] = *(const bf16x8*)&As_f[base + aOff[i]];
#pragma unroll
      for (int j = 0; j < 4; ++j) bF[j] = *(const bf16x8*)&Bs_f[base + bOff[j]];
      if (kt + 1 < NT) {
        STAGE_A(kt + 1, 0, 0); STAGE_A(kt + 1, 0, 1);
        STAGE_B(kt + 1, 0, 0); STAGE_B(kt + 1, 0, 1);
        STAGE_A(kt + 1, 1, 0); STAGE_A(kt + 1, 1, 1);
      }
      __builtin_amdgcn_s_setprio(1);
#pragma unroll
      for (int i = 0; i < 8; ++i)
#pragma unroll
        for (int j = 0; j < 4; ++j)
          acc[i][j] = __builtin_amdgcn_mfma_f32_16x16x32_bf16(aF[i], bF[j], acc[i][j], 0, 0, 0);
      __builtin_amdgcn_s_setprio(0);
    }
    if (kt + 1 < NT) { asm volatile("s_waitcnt vmcnt(6)" ::: "memory"); }
    else             { asm volatile("s_waitcnt vmcnt(0)" ::: "memory"); }
    __builtin_amdgcn_s_barrier();
    __builtin_amdgcn_sched_barrier(0);
    {   // phase 1: khalf 1
      const int base = (b * 2 + 1) * 8192;
      bf16x8 aF[8], bF[4];
#pragma unroll
      for (int i = 0; i < 8; ++i) aF[i] = *(const bf16x8*)&As_f[base + aOff[i]];
#pragma unroll
      for (int j = 0; j < 4; ++j) bF[j] = *(const bf16x8*)&Bs_f[base + bOff[j]];
      if (kt + 1 < NT) { STAGE_B(kt + 1, 1, 0); STAGE_B(kt + 1, 1, 1); }
      __builtin_amdgcn_s_setprio(1);
#pragma unroll
      for (int i = 0; i < 8; ++i)
#pragma unroll
        for (int j = 0; j < 4; ++j)
          acc[i][j] = __builtin_amdgcn_mfma_f32_16x16x32_bf16(aF[i], bF[j], acc[i][j], 0, 0, 0);
      __builtin_amdgcn_s_setprio(0);
    }
  }

  // epilogue: LDS-bounce, contiguous row writes
  float* eb = (float*)lds_all;               // [64][261] f32
  const int lq = (lane >> 4) * 4;
  float bv4[4];
#pragma unroll
  for (int j = 0; j < 4; ++j) bv4[j] = biasPad[n0 + wn * 64 + j * 16 + (lane & 15)];

#pragma unroll
  for (int cp = 0; cp < 4; ++cp) {
    __syncthreads();
#pragma unroll
    for (int ii = 0; ii < 2; ++ii) {
      int rbase = wm * 32 + ii * 16 + lq;
#pragma unroll
      for (int j = 0; j < 4; ++j) {
        int col = wn * 64 + j * 16 + (lane & 15);
#pragma unroll
        for (int r = 0; r < 4; ++r)
          eb[(rbase + r) * 261 + col] = acc[cp * 2 + ii][j][r] + bv4[j];
      }
    }
    __syncthreads();
    {
      int rl = tid >> 3, ci = tid & 7;
      long grow = (long)m0 + (rl >> 5) * 128 + cp * 32 + (rl & 31);
      float* crow = C + grow * N + n0;
      const float* er = &eb[rl * 261];
#pragma unroll
      for (int k = 0; k < 8; ++k) {
        int col = ci * 4 + k * 32;
        float4 v = *(const float4*)&er[col];
        int gc = n0 + col;
        if (gc + 4 <= N) {
          *(float4*)&crow[col] = v;
        } else if (gc < N) {
          float tmp[4] = {v.x, v.y, v.z, v.w};
#pragma unroll
          for (int e = 0; e < 4; ++e)
            if (gc + e < N) crow[col + e] = tmp[e];
        }
      }
    }
  }
}

// ---------------- joint = bf16(relu(enc_p[b,t,:] + prd_p[b,u,:])) ----------------
__global__ void k_joint(const float* __restrict__ ep, const float* __restrict__ pp,
                        unsigned short* __restrict__ jt)
{
  int idx = blockIdx.x * 256 + threadIdx.x;
  int m = idx >> 8;
  int kc = (idx & 255) << 2;
  int erow = m >> 6;
  int prow = (m >> 13) * U_ + (m & 63);
  const float4 e = *(const float4*)&ep[erow * H_ + kc];
  const float4 p = *(const float4*)&pp[prow * H_ + kc];
  float4 s;
  s.x = fmaxf(e.x + p.x, 0.f); s.y = fmaxf(e.y + p.y, 0.f);
  s.z = fmaxf(e.z + p.z, 0.f); s.w = fmaxf(e.w + p.w, 0.f);
  ushort4 o; o.x = f2bf(s.x); o.y = f2bf(s.y); o.z = f2bf(s.z); o.w = f2bf(s.w);
  *(ushort4*)&jt[m * H_ + kc] = o;
}

// ---------------- fused 2-layer wavefront LSTM, 4 groups x 64 blocks x 256 thr ----------------
// (round-13/16 proven version — VALU dot, 306 us)
__global__ __launch_bounds__(256, 1) void lstm_fused3(
    const unsigned short* __restrict__ x0_bf,
    const unsigned short* __restrict__ Whh0,
    const unsigned short* __restrict__ Wih0,
    const unsigned short* __restrict__ Whh1,
    const unsigned short* __restrict__ Wih1,
    const float* __restrict__ bih0, const float* __restrict__ bhh0,
    const float* __restrict__ bih1, const float* __restrict__ bhh1,
    unsigned short* __restrict__ x2_bf,
    float* __restrict__ hbuf0,
    float* __restrict__ hbuf1,
    float* __restrict__ xbuf,
    float* __restrict__ xg1buf, int* __restrict__ flags1,
    float* __restrict__ xg0buf, int* __restrict__ flags0)
{
  __shared__ float hs[2][H_];
  __shared__ float part[2][4][64][2];
  __shared__ float biasS[64];

  const int tid = threadIdx.x;
  const int grp = blockIdx.x >> 6;           // 0=L0, 1=X1, 2=L1, 3=X0
  const int bid = blockIdx.x & 63;
  const int w = tid >> 6, l = tid & 63;
  const int g = l >> 4, q = l & 15;
  const int row = g * 1024 + bid * 16 + q;
  const int kb = w * 256;

#define DOT_BODY(WREG, SRC)                                                              \
  _Pragma("unroll")                                                                      \
  for (int it = 0; it < 32; ++it) {                                                      \
    bf16x8 wv = WREG[it];                                                                \
    float4 h0a = *(const float4*)&SRC[0][kb + it * 8];                                   \
    float4 h0b = *(const float4*)&SRC[0][kb + it * 8 + 4];                               \
    float4 h1a = *(const float4*)&SRC[1][kb + it * 8];                                   \
    float4 h1b = *(const float4*)&SRC[1][kb + it * 8 + 4];                               \
    a00 += bf2f((unsigned short)wv[0]) * h0a.x + bf2f((unsigned short)wv[4]) * h0b.x;    \
    a01 += bf2f((unsigned short)wv[1]) * h0a.y + bf2f((unsigned short)wv[5]) * h0b.y;    \
    a02 += bf2f((unsigned short)wv[2]) * h0a.z + bf2f((unsigned short)wv[6]) * h0b.z;    \
    a03 += bf2f((unsigned short)wv[3]) * h0a.w + bf2f((unsigned short)wv[7]) * h0b.w;    \
    a10 += bf2f((unsigned short)wv[0]) * h1a.x + bf2f((unsigned short)wv[4]) * h1b.x;    \
    a11 += bf2f((unsigned short)wv[1]) * h1a.y + bf2f((unsigned short)wv[5]) * h1b.y;    \
    a12 += bf2f((unsigned short)wv[2]) * h1a.z + bf2f((unsigned short)wv[6]) * h1b.z;    \
    a13 += bf2f((unsigned short)wv[3]) * h1a.w + bf2f((unsigned short)wv[7]) * h1b.w;    \
  }

  if (grp == 0 || grp == 2) {
    const unsigned short* Whh = (grp == 0) ? Whh0 : Whh1;
    float* hbuf   = (grp == 0) ? hbuf0 : hbuf1;
    const float* xgbufR = (grp == 0) ? xg0buf : xg1buf;
    const int* flagsR   = (grp == 0) ? flags0 : flags1;
    bf16x8 wreg[32];
#pragma unroll
    for (int it = 0; it < 32; ++it)
      wreg[it] = *(const bf16x8*)&Whh[(long)row * H_ + kb + it * 8];
    __syncthreads();

    float creg = 0.f;
    for (int u = 0; u < U_; ++u) {
      const int p = u & 1;
      float xgi = 0.f, xgf = 0.f, xgg = 0.f, xgo = 0.f;
      if (tid < 32) {
        const int* fp = &flagsR[(u * 64 + bid) * 16];
        int fv;
        for (;;) {
          asm volatile("global_load_dword %0, %1, off sc1\n\ts_waitcnt vmcnt(0)"
                       : "=v"(fv) : "v"(fp) : "memory");
          if (fv != 0) break;
          __builtin_amdgcn_s_sleep(8);
        }
        const float* xb = &xgbufR[((u * 64 + bid) * 2 + (tid >> 4)) * 64];
        int qq = tid & 15;
        asm volatile("global_load_dword %0, %1, off sc1" : "=&v"(xgi) : "v"(xb + qq) : "memory");
        asm volatile("global_load_dword %0, %1, off sc1" : "=&v"(xgf) : "v"(xb + 16 + qq) : "memory");
        asm volatile("global_load_dword %0, %1, off sc1" : "=&v"(xgg) : "v"(xb + 32 + qq) : "memory");
        asm volatile("global_load_dword %0, %1, off sc1" : "=&v"(xgo) : "v"(xb + 48 + qq) : "memory");
      }
      float a00 = 0.f, a01 = 0.f, a02 = 0.f, a03 = 0.f;
      float a10 = 0.f, a11 = 0.f, a12 = 0.f, a13 = 0.f;
      if (u > 0) {
        const float thr = 4.0f * u - 2.0f;
        const float* base = hbuf + (u & 1) * 2 * H_;
        const float* pa = base + tid * 4;
        const float* pb = base + H_ + tid * 4;
        float4 va, vb;
        for (;;) {
          asm volatile("global_load_dwordx4 %0, %2, off sc1\n\t"
                       "global_load_dwordx4 %1, %3, off sc1\n\t"
                       "s_waitcnt vmcnt(0)"
                       : "=v"(va), "=v"(vb) : "v"(pa), "v"(pb) : "memory");
          if (va.x > thr && va.y > thr && va.z > thr && va.w > thr &&
              vb.x > thr && vb.y > thr && vb.z > thr && vb.w > thr) break;
          __builtin_amdgcn_s_sleep(8);
        }
        const float off = 4.0f * u;
        va.x -= off; va.y -= off; va.z -= off; va.w -= off;
        vb.x -= off; vb.y -= off; vb.z -= off; vb.w -= off;
        *(float4*)&hs[0][tid * 4] = va;
        *(float4*)&hs[1][tid * 4] = vb;
        DOT_BODY(wreg, hs)
      }
      part[p][w][l][0] = (a00 + a01) + (a02 + a03);
      part[p][w][l][1] = (a10 + a11) + (a12 + a13);
      if (tid < 32) {
        asm volatile("s_waitcnt vmcnt(0)"
                     : "+v"(xgi), "+v"(xgf), "+v"(xgg), "+v"(xgo) :: "memory");
      }
      __syncthreads();
      if (tid < 32) {
        int b = tid >> 4, qq = tid & 15;
        float gi = part[p][0][qq][b] + part[p][1][qq][b] + part[p][2][qq][b]
                 + part[p][3][qq][b] + xgi;
        float gf = part[p][0][16 + qq][b] + part[p][1][16 + qq][b] + part[p][2][16 + qq][b]
                 + part[p][3][16 + qq][b] + xgf;
        float gc = part[p][0][32 + qq][b] + part[p][1][32 + qq][b] + part[p][2][32 + qq][b]
                 + part[p][3][32 + qq][b] + xgg;
        float go = part[p][0][48 + qq][b] + part[p][1][48 + qq][b] + part[p][2][48 + qq][b]
                 + part[p][3][48 + qq][b] + xgo;
        float i_ = fsig(gi), f_ = fsig(gf), g_ = ftanh(gc), o_ = fsig(go);
        creg = f_ * creg + i_ * g_;
        float h = o_ * ftanh(creg);
        int j = bid * 16 + qq;
        if (grp == 0) {
          float tvx = h + 4.0f;
          const float* px = &xbuf[u * 2 * H_ + b * H_ + j];
          asm volatile("global_store_dword %0, %1, off sc1" :: "v"(px), "v"(tvx) : "memory");
        } else {
          x2_bf[(b * U_ + u) * H_ + j] = f2bf(h);
        }
        if (u < U_ - 1) {
          float tv = h + 4.0f * (u + 1);
          const float* pp2 = &hbuf[((u + 1) & 1) * 2 * H_ + b * H_ + j];
          asm volatile("global_store_dword %0, %1, off sc1" :: "v"(pp2), "v"(tv) : "memory");
        }
      }
    }
  } else {
    const bool isX1 = (grp == 1);
    const unsigned short* Wih = isX1 ? Wih1 : Wih0;
    const float* bihp = isX1 ? bih1 : bih0;
    const float* bhhp = isX1 ? bhh1 : bhh0;
    float* xgbufW = isX1 ? xg1buf : xg0buf;
    int* flagsW   = isX1 ? flags1 : flags0;
    bf16x8 wreg[32];
#pragma unroll
    for (int it = 0; it < 32; ++it)
      wreg[it] = *(const bf16x8*)&Wih[(long)row * H_ + kb + it * 8];
    if (tid < 64) {
      int rr = (tid >> 4) * 1024 + bid * 16 + (tid & 15);
      biasS[tid] = bihp[rr] + bhhp[rr];
    }
    __syncthreads();

    for (int u = 0; u < U_; ++u) {
      const int p = u & 1;
      if (isX1) {
        const float* base = xbuf + u * 2 * H_;
        const float* pa = base + tid * 4;
        const float* pb = base + H_ + tid * 4;
        float4 va, vb;
        for (;;) {
          asm volatile("global_load_dwordx4 %0, %2, off sc1\n\t"
                       "global_load_dwordx4 %1, %3, off sc1\n\t"
                       "s_waitcnt vmcnt(0)"
                       : "=v"(va), "=v"(vb) : "v"(pa), "v"(pb) : "memory");
          if (va.x > 2.f && va.y > 2.f && va.z > 2.f && va.w > 2.f &&
              vb.x > 2.f && vb.y > 2.f && vb.z > 2.f && vb.w > 2.f) break;
          __builtin_amdgcn_s_sleep(8);
        }
        va.x -= 4.f; va.y -= 4.f; va.z -= 4.f; va.w -= 4.f;
        vb.x -= 4.f; vb.y -= 4.f; vb.z -= 4.f; vb.w -= 4.f;
        *(float4*)&hs[0][tid * 4] = va;
        *(float4*)&hs[1][tid * 4] = vb;
      } else {
        ushort4 xa = *(const ushort4*)&x0_bf[(0 * U_ + u) * H_ + tid * 4];
        ushort4 xb = *(const ushort4*)&x0_bf[(1 * U_ + u) * H_ + tid * 4];
        float4 va, vb;
        va.x = bf2f(xa.x); va.y = bf2f(xa.y); va.z = bf2f(xa.z); va.w = bf2f(xa.w);
        vb.x = bf2f(xb.x); vb.y = bf2f(xb.y); vb.z = bf2f(xb.z); vb.w = bf2f(xb.w);
        *(float4*)&hs[0][tid * 4] = va;
        *(float4*)&hs[1][tid * 4] = vb;
      }

      float a00 = 0.f, a01 = 0.f, a02 = 0.f, a03 = 0.f;
      float a10 = 0.f, a11 = 0.f, a12 = 0.f, a13 = 0.f;
      DOT_BODY(wreg, hs)
      part[p][w][l][0] = (a00 + a01) + (a02 + a03);
      part[p][w][l][1] = (a10 + a11) + (a12 + a13);
      __syncthreads();
      if (tid < 128) {
        int b = tid >> 6, ll = tid & 63;
        float s = part[p][0][ll][b] + part[p][1][ll][b] + part[p][2][ll][b]
                + part[p][3][ll][b] + biasS[ll];
        const float* pw = &xgbufW[((u * 64 + bid) * 2 + b) * 64 + ll];
        asm volatile("global_store_dword %0, %1, off sc1" :: "v"(pw), "v"(s) : "memory");
        asm volatile("s_waitcnt vmcnt(0)" ::: "memory");
      }
      __syncthreads();
      if (tid == 0) {
        int one = 1;
        const int* fp = &flagsW[(u * 64 + bid) * 16];
        asm volatile("global_store_dword %0, %1, off sc1" :: "v"(fp), "v"(one) : "memory");
      }
    }
  }
#undef DOT_BODY
}

extern "C" void kernel_launch(void* const* d_in, const int* in_sizes, int n_in,
                              void* d_out, int out_size, void* d_ws, size_t ws_size,
                              hipStream_t stream)
{
  const float* enc   = (const float*)d_in[0];
  const int*   tg    = (const int*)d_in[1];
  const float* em    = (const float*)d_in[2];
  const float* Wih   = (const float*)d_in[3];
  const float* Whh   = (const float*)d_in[4];
  const float* bih   = (const float*)d_in[5];
  const float* bhh   = (const float*)d_in[6];
  const float* encW  = (const float*)d_in[7];
  const float* encB  = (const float*)d_in[8];
  const float* prdW  = (const float*)d_in[9];
  const float* prdB  = (const float*)d_in[10];
  const float* outW  = (const float*)d_in[11];
  const float* outB  = (const float*)d_in[12];
  float* out = (float*)d_out;
  char* ws = (char*)d_ws;

  // workspace layout (bytes)
  unsigned short* outW_bf = (unsigned short*)(ws + 0);         // 10,485,760
  unsigned short* Wih_bf  = (unsigned short*)(ws + 10485760);
  unsigned short* Whh_bf  = (unsigned short*)(ws + 27262976);
  unsigned short* encW_bf = (unsigned short*)(ws + 44040192);
  unsigned short* prdW_bf = (unsigned short*)(ws + 46137344);
  unsigned short* enc_bf  = (unsigned short*)(ws + 48234496);
  unsigned short* x0_bf   = (unsigned short*)(ws + 48758784);
  unsigned short* x2_bf   = (unsigned short*)(ws + 49283072);
  float* xg1buf = (float*)(ws + 49545216);                     // 2MB, live during LSTM
  float* hbufL0 = (float*)(ws + 51642368);                     // 16,384
  unsigned short* jt = (unsigned short*)(ws + 51659008);       // 32MB -> ends 85,213,440
  // flags0/xg0buf alias the head of the jt region (time-disjoint: jt written by
  // k_joint only AFTER the LSTM completes) — proven since round 13.
  int*   flags0 = (int*)(ws + 51659008);                       // 262,144
  float* xg0buf = (float*)(ws + 51921152);                     // 2,097,152
  float* hbufL1 = (float*)(ws + 85213440);                     // 16,384
  float* biasPad = (float*)(ws + 85229824);                    // 20,480
  float* xbuf = (float*)(ws + 85250304);                       // 524,288
  int* flags1 = (int*)(ws + 85774592);                         // 262,144 -> 86,036,736
  float* ep = (float*)(ws + 49545216);                         // post-LSTM overlap w/ xg1buf
  float* pp = (float*)(ws + 49545216 + 1048576);

  hipMemsetAsync(hbufL0, 0, 16384, stream);
  hipMemsetAsync(hbufL1, 0, 86036736 - 85213440, stream);      // hbufL1..flags1 end
  hipMemsetAsync(flags0, 0, 262144, stream);

  k_cvt_all<<<R_EMB / 256, 256, 0, stream>>>(
      outW, Wih, Whh, encW, prdW, enc, outB, tg, em,
      outW_bf, Wih_bf, Whh_bf, encW_bf, prdW_bf, enc_bf, biasPad, x0_bf);

  // ---- fused 4-group LSTM (both input projections in-kernel) ----
  lstm_fused3<<<256, 256, 0, stream>>>(
      x0_bf,
      Whh_bf, Wih_bf,
      Whh_bf + 4096 * H_, Wih_bf + 4096 * H_,
      bih, bhh, bih + 4096, bhh + 4096,
      x2_bf, hbufL0, hbufL1, xbuf,
      xg1buf, flags1, xg0buf, flags0);

  // ---- projections (ep + pp in one launch) ----
  gemm_proj<<<dim3(8, 3), 256, 0, stream>>>(enc_bf, x2_bf, encW_bf, prdW_bf,
                                            encB, prdB, ep, pp);

  // ---- joint + logits ----
  k_joint<<<16384, 256, 0, stream>>>(ep, pp, jt);
  gemm_logits<<<1280, 512, 0, stream>>>(jt, outW_bf, biasPad, out, B_ * T_ * U_, NO_, H_);
}